// Round 6
// baseline (95.306 us; speedup 1.0000x reference)
//
#include <hip/hip_runtime.h>

// PatchMMD: x,y are (64,1,64,64) fp32. For pairs (i,j):
//   D(i,j,p,q) = sum_{3x3 window at (p,q)} (A_i - B_j)^2   (VALID -> 62x62)
//   K = exp(-D / (2*(0.5*9)^2)) = exp(-D/40.5)
// out = offdiag_mean(Kxx) - 2*mean(Kxy) + offdiag_mean(Kyy)
//
// Round 6: column-per-lane, A-register-resident, zero LDS / zero barriers.
//  - lane c owns column c of the image; vertical 3-sum = register sliding
//    window; horizontal 3-sum = two whole-wave DPP shifts (WAVE_SHL1 0x130)
//  - wave holds image A in 64 VGPRs, streams B one contiguous 256B row-load
//    at a time; 2 pairs per wave share the same A (sorted flat pair list)
//  - 64-lane reduce = DPP shr1/2/4/8 + bcast15/31 chain (pure VALU)
//  - fp32 partials per wave; fp64 only in the tiny reduce kernel
//  - symmetry: xx/yy only i<j (sqrt triangular decode), doubled at combine

#define NPAIR_TRI 2016   // 64*63/2
#define NPAIRS    8128   // 2*2016 + 4096
#define NWAVES    4064   // 2 pairs per wave
#define NBLOCKS   1016   // 4 waves per block

#if __has_builtin(__builtin_amdgcn_exp2f)
#define EXP2F(v) __builtin_amdgcn_exp2f(v)
#else
#define EXP2F(v) __expf((v) * 0.69314718055994530942f)
#endif

// DPP mov with 0-fill (bound_ctrl=1). 0x130 = WAVE_SHL1: lane i <- lane i+1
// across the whole wave (same direction as row_shl:1 = 0x101, validated R4/R5).
template<int CTRL>
__device__ __forceinline__ float dpp0_f(float v) {
    int r = __builtin_amdgcn_update_dpp(0, __float_as_int(v), CTRL, 0xf, 0xf, true);
    return __int_as_float(r);
}
// row-masked DPP (masked-off rows contribute old=0 to the add)
template<int CTRL, int RM>
__device__ __forceinline__ float dppm_f(float v) {
    int r = __builtin_amdgcn_update_dpp(0, __float_as_int(v), CTRL, RM, 0xf, true);
    return __int_as_float(r);
}

// full 64-lane sum, result in lane 63 (classic gfx9 DPP reduce)
__device__ __forceinline__ float wave_reduce_f(float v) {
    v += dpp0_f<0x111>(v);            // row_shr:1
    v += dpp0_f<0x112>(v);            // row_shr:2
    v += dpp0_f<0x114>(v);            // row_shr:4
    v += dpp0_f<0x118>(v);            // row_shr:8  -> lane 15 of each row
    v += dppm_f<0x142, 0xa>(v);       // bcast15 into rows 1,3
    v += dppm_f<0x143, 0xc>(v);       // bcast31 into rows 2,3 -> lane 63 total
    return v;
}

__global__ __launch_bounds__(256, 4) void mmd_pair_kernel(
    const float* __restrict__ x, const float* __restrict__ y,
    float* __restrict__ partials)
{
    const int t    = threadIdx.x;
    const int wid  = t >> 6;
    const int lane = t & 63;
    const int w    = blockIdx.x * 4 + wid;     // 0..4063, exact

    const float NEG_SCALE = -1.0f / (40.5f * 0.69314718055994530942f);  // exp2 scale
    const bool  poison    = (lane >= 62);      // cols 62,63 have no valid window

    float acc_off = 0.0f, acc_xy = 0.0f;
    float areg[64];
    const float* curA = nullptr;

    for (int p = 0; p < 2; ++p) {
        const int pid = 2 * w + p;             // < 8128

        // decode pair: [0,2016) xx i<j; [2016,4032) yy i<j; [4032,8128) xy all
        const float *Abase, *Bbase;
        bool is_xy;
        if (pid < 2 * NPAIR_TRI) {
            is_xy = false;
            const float* base = (pid < NPAIR_TRI) ? x : y;
            int k = (pid < NPAIR_TRI) ? pid : pid - NPAIR_TRI;
            // i = floor((127 - sqrt(127^2 - 8k))/2), +-1 fixup for fp rounding
            float s = sqrtf(16129.0f - 8.0f * (float)k);
            int i = (int)floorf((127.0f - s) * 0.5f);
            int b = (i * (127 - i)) >> 1;
            if (k < b) { --i; b = (i * (127 - i)) >> 1; }
            else { int nb = ((i + 1) * (126 - i)) >> 1; if (k >= nb) { ++i; b = nb; } }
            int j = i + 1 + (k - b);
            Abase = base + i * 4096; Bbase = base + j * 4096;
        } else {
            is_xy = true;
            int e = pid - 2 * NPAIR_TRI;
            Abase = x + (e >> 6) * 4096; Bbase = y + (e & 63) * 4096;
        }

        // (re)load resident A: 64 coalesced 256B row-loads into 64 VGPRs
        if (Abase != curA) {
            curA = Abase;
            #pragma unroll
            for (int r = 0; r < 64; ++r)
                areg[r] = Abase[r * 64 + lane];
        }

        // stream B rows; h via 2 wave-shifts; vertical 3-sum slides in regs
        float accp = 0.0f, hp1 = 0.0f, sp = 0.0f;
        #pragma unroll
        for (int r = 0; r < 64; ++r) {
            float bv = Bbase[r * 64 + lane];
            float d  = areg[r] - bv;
            d *= d;
            float t1 = dpp0_f<0x130>(d);       // d[c+1] (0 at lane 63)
            float t2 = dpp0_f<0x130>(t1);      // d[c+2]
            float h  = (d + t1) + t2;
            h = poison ? 1e30f : h;            // invalid cols -> exp == 0
            if (r >= 2) {
                float D = sp + h;              // h[r-2]+h[r-1]+h[r]
                accp += EXP2F(D * NEG_SCALE);
            }
            sp  = hp1 + h;                     // becomes h[r-1]+h[r]
            hp1 = h;
        }
        if (is_xy) acc_xy += accp; else acc_off += accp;
    }

    acc_off = wave_reduce_f(acc_off);
    acc_xy  = wave_reduce_f(acc_xy);
    if (lane == 63) {
        partials[w]          = acc_off;
        partials[NWAVES + w] = acc_xy;
    }
}

__global__ __launch_bounds__(256) void mmd_reduce_kernel(
    const float* __restrict__ partials, float* __restrict__ out)
{
    const int t = threadIdx.x;
    double a_off = 0.0, a_xy = 0.0;
    for (int e = t; e < NWAVES; e += 256) {
        a_off += (double)partials[e];
        a_xy  += (double)partials[NWAVES + e];
    }
    #pragma unroll
    for (int off = 32; off > 0; off >>= 1) {
        a_off += __shfl_xor(a_off, off);
        a_xy  += __shfl_xor(a_xy,  off);
    }
    __shared__ double wsm[2][4];
    const int lane = t & 63, wd = t >> 6;
    if (lane == 0) { wsm[0][wd] = a_off; wsm[1][wd] = a_xy; }
    __syncthreads();
    if (t == 0) {
        double so = wsm[0][0] + wsm[0][1] + wsm[0][2] + wsm[0][3];  // half off-diag
        double sx = wsm[1][0] + wsm[1][1] + wsm[1][2] + wsm[1][3];
        const double cnt_off = 64.0 * 63.0 * 62.0 * 62.0;   // N*(N-1)*h*w
        const double cnt_all = 64.0 * 64.0 * 62.0 * 62.0;   // N*N*h*w
        out[0] = (float)(2.0 * so / cnt_off - 2.0 * sx / cnt_all);
    }
}

extern "C" void kernel_launch(void* const* d_in, const int* in_sizes, int n_in,
                              void* d_out, int out_size, void* d_ws, size_t ws_size,
                              hipStream_t stream) {
    const float* x = (const float*)d_in[0];
    const float* y = (const float*)d_in[1];
    float* out = (float*)d_out;
    float* partials = (float*)d_ws;   // 8128 floats = 32.5 KiB

    mmd_pair_kernel<<<NBLOCKS, 256, 0, stream>>>(x, y, partials);
    mmd_reduce_kernel<<<1, 256, 0, stream>>>(partials, out);
}

// Round 7
// 35.104 us; speedup vs baseline: 2.7150x; 2.7150x over previous
//
#include <hip/hip_runtime.h>

// PatchMMD via MFMA patch-GEMM.
//   D(i,j,p,q) = ||patch_i(p,q) - patch_j(p,q)||^2  (3x3, VALID -> 62x62)
//   K = exp(-D/40.5);  out = offmean(Kxx) - 2*mean(Kxy) + offmean(Kyy)
//
// Key identity: D = pre_i + pre_j - 2*cross_ij with cross_ij = <patch_i, patch_j>.
// Stack all 128 images (x then y): the 128x128 cross matrix per position is a
// K=9 GEMM -> mfma_f32_16x16x32_bf16 tiles. The matrix is symmetric ->
// compute 36 lower-tri 16x16 tiles; diag tiles' diagonals ARE pre (Box(a^2)).
// Diagonal elements give exp2(~0)=1: subtract 128*3844 at the end (no masks).
//
// Pipeline: (1) im2col -> bf16 K-records in d_ws (15.7 MB), (2) wave-per-
// position MFMA kernel, (3) tiny fp64 combine. Falls back to the verified
// R4 LDS kernel when ws_size is too small.

typedef __attribute__((ext_vector_type(8))) short short8v;
typedef __attribute__((ext_vector_type(4))) float f32x4;
typedef __attribute__((ext_vector_type(4))) int   int4v;

#define NPOS    3844                    // 62*62 positions
#define RECB    ((size_t)NPOS * 128 * 32)   // 15,745,024 B of K-records
#define WSNEED  (RECB + (size_t)3 * 4096 * 4)

#if __has_builtin(__builtin_amdgcn_exp2f)
#define EXP2F(v) __builtin_amdgcn_exp2f(v)
#else
#define EXP2F(v) __expf((v) * 0.69314718055994530942f)
#endif

// ---------------- DPP helpers (validated R4/R6) ----------------
template<int CTRL>
__device__ __forceinline__ float dpp0_f(float v) {
    int r = __builtin_amdgcn_update_dpp(0, __float_as_int(v), CTRL, 0xf, 0xf, true);
    return __int_as_float(r);
}
template<int CTRL, int RM>
__device__ __forceinline__ float dppm_f(float v) {
    int r = __builtin_amdgcn_update_dpp(0, __float_as_int(v), CTRL, RM, 0xf, true);
    return __int_as_float(r);
}
__device__ __forceinline__ float wave_reduce_f(float v) {
    v += dpp0_f<0x111>(v);            // row_shr:1
    v += dpp0_f<0x112>(v);            // row_shr:2
    v += dpp0_f<0x114>(v);            // row_shr:4
    v += dpp0_f<0x118>(v);            // row_shr:8  -> lane 15 of each row
    v += dppm_f<0x142, 0xa>(v);       // bcast15 into rows 1,3
    v += dppm_f<0x143, 0xc>(v);       // bcast31 into rows 2,3 -> lane 63 total
    return v;
}

// ---------------- kernel 1: im2col to bf16 K-records ----------------
// rec[pos][n][32 bf16]: k=0..8 = 3x3 patch (row-major), k=9..31 = 0 (k>=16
// implicit: MFMA lanes 32..63 load zeros in-register). 124 blocks = 62 rows x 2.
__global__ __launch_bounds__(256) void im2col_kernel(
    const float* __restrict__ x, const float* __restrict__ y,
    unsigned char* __restrict__ rec)
{
    __shared__ float stg[128 * 195];   // [img][u*64+c], stride 195: bank-spread
    const int t = threadIdx.x;
    const int p = blockIdx.x >> 1;     // output row 0..61
    const int h = blockIdx.x & 1;      // q half

    // stage rows p..p+2 of all 128 images (coalesced float4 global loads)
    for (int i4 = t; i4 < 128 * 3 * 16; i4 += 256) {
        int cg = i4 & 15, u = (i4 >> 4) % 3, n = i4 / 48;
        const float* img = (n < 64) ? (x + n * 4096) : (y + (n - 64) * 4096);
        float4 v = *reinterpret_cast<const float4*>(img + (p + u) * 64 + cg * 4);
        float* d = stg + n * 195 + u * 64 + cg * 4;
        d[0] = v.x; d[1] = v.y; d[2] = v.z; d[3] = v.w;
    }
    __syncthreads();

    // build records: lane-consecutive n -> coalesced 32B stores
    for (int rid = t; rid < 31 * 128; rid += 256) {
        int n = rid & 127, ql = rid >> 7;
        int q = h * 31 + ql;
        const float* s = stg + n * 195 + q;
        unsigned short b[9];
        #pragma unroll
        for (int u = 0; u < 3; ++u)
            #pragma unroll
            for (int v = 0; v < 3; ++v) {
                unsigned int ui = __float_as_uint(s[u * 64 + v]);
                b[u * 3 + v] = (unsigned short)((ui + 0x7fffu + ((ui >> 16) & 1u)) >> 16);
            }
        int pos = p * 62 + q;
        int4v* dst = reinterpret_cast<int4v*>(rec + ((size_t)(pos * 128 + n) << 5));
        int4v lo = { (int)(b[0] | ((unsigned)b[1] << 16)),
                     (int)(b[2] | ((unsigned)b[3] << 16)),
                     (int)(b[4] | ((unsigned)b[5] << 16)),
                     (int)(b[6] | ((unsigned)b[7] << 16)) };
        int4v hi = { (int)(unsigned)b[8], 0, 0, 0 };
        dst[0] = lo; dst[1] = hi;
    }
}

// ---------------- kernel 2: wave-per-position MFMA ----------------
__global__ __launch_bounds__(256) void mmd_mfma_kernel(
    const unsigned char* __restrict__ rec, float* __restrict__ part)
{
    const int t = threadIdx.x, wid = t >> 6, lane = t & 63;
    const int pid = blockIdx.x * 4 + wid;        // 0..3843 (961*4 exact)
    __shared__ float pre[4][128];

    const float NS   = -1.0f / (40.5f * 0.69314718055994530942f);  // exp2 scale
    const float M2NS = -2.0f * NS;
    const int   kg   = lane >> 4;                // k-group 0..3

    // 8 shared fragments: frag[g] serves as BOTH A and B operand (identical
    // lane layouts: row/col = lane&15, k = (lane>>4)*8+e). Lanes>=32 hold the
    // K=16..31 zero padding in-register.
    short8v frag[8];
    const short8v zero8 = {0,0,0,0,0,0,0,0};
    #pragma unroll
    for (int g = 0; g < 8; ++g) {
        if (lane < 32) {
            const unsigned char* p = rec + (((size_t)pid * 128 + g * 16 + (lane & 15)) << 5)
                                   + (size_t)(kg << 4);
            frag[g] = *reinterpret_cast<const short8v*>(p);
        } else frag[g] = zero8;
    }

    const f32x4 zf = {0.f, 0.f, 0.f, 0.f};

    // diagonal tiles: C[r,c] = <patch_r, patch_c> within group g; diag = pre
    f32x4 accd[8];
    #pragma unroll
    for (int g = 0; g < 8; ++g)
        accd[g] = __builtin_amdgcn_mfma_f32_16x16x32_bf16(frag[g], frag[g], zf, 0, 0, 0);

    // extract NS*diag to LDS (holder lanes: row==col). C/D: col=lane&15,
    // row=(lane>>4)*4+m  -> holder iff (lane>>2)&3 == lane>>4, m = lane&3.
    const bool holder = ((lane >> 2) & 3) == kg;
    #pragma unroll
    for (int g = 0; g < 8; ++g) {
        float lo = (lane & 1) ? accd[g][1] : accd[g][0];
        float hi = (lane & 1) ? accd[g][3] : accd[g][2];
        float v  = (lane & 2) ? hi : lo;
        if (holder) pre[wid][g * 16 + (lane & 15)] = NS * v;
    }
    __syncthreads();

    // per-lane pre slices: pa[g][m] = rows of this lane's C elems, pb[g] = col
    float pa[8][4], pb[8];
    #pragma unroll
    for (int g = 0; g < 8; ++g) {
        const float* pp = &pre[wid][g * 16 + kg * 4];
        pa[g][0] = pp[0]; pa[g][1] = pp[1]; pa[g][2] = pp[2]; pa[g][3] = pp[3];
        pb[g] = pre[wid][g * 16 + (lane & 15)];
    }

    float acc_diag = 0.f, acc_same = 0.f, acc_cross = 0.f;

    // diag-tile epilogue (full tiles; r==c elems give exp2(~0)=1, removed later)
    #pragma unroll
    for (int g = 0; g < 8; ++g)
        #pragma unroll
        for (int m = 0; m < 4; ++m)
            acc_diag += EXP2F(fmaf(accd[g][m], M2NS, pa[g][m] + pb[g]));

    // 28 strict-lower tiles: same-half weight 2, cross (y vs x) weight 1
    #pragma unroll
    for (int ti = 1; ti < 8; ++ti)
        #pragma unroll
        for (int tj = 0; tj < ti; ++tj) {
            f32x4 c4 = __builtin_amdgcn_mfma_f32_16x16x32_bf16(frag[ti], frag[tj], zf, 0, 0, 0);
            float e = 0.f;
            #pragma unroll
            for (int m = 0; m < 4; ++m)
                e += EXP2F(fmaf(c4[m], M2NS, pa[ti][m] + pb[tj]));
            if (ti >= 4 && tj < 4) acc_cross += e; else acc_same += e;
        }

    acc_diag  = wave_reduce_f(acc_diag);
    acc_same  = wave_reduce_f(acc_same);
    acc_cross = wave_reduce_f(acc_cross);
    if (lane == 63) {
        part[pid]        = acc_diag;
        part[4096 + pid] = acc_same;
        part[8192 + pid] = acc_cross;
    }
}

// ---------------- kernel 3: fp64 combine ----------------
__global__ __launch_bounds__(256) void mmd_final_kernel(
    const float* __restrict__ part, float* __restrict__ out)
{
    const int t = threadIdx.x;
    double sd = 0.0, ss = 0.0, sc = 0.0;
    for (int e = t; e < NPOS; e += 256) {
        sd += (double)part[e];
        ss += (double)part[4096 + e];
        sc += (double)part[8192 + e];
    }
    #pragma unroll
    for (int off = 32; off > 0; off >>= 1) {
        sd += __shfl_xor(sd, off);
        ss += __shfl_xor(ss, off);
        sc += __shfl_xor(sc, off);
    }
    __shared__ double w[3][4];
    const int lane = t & 63, wd = t >> 6;
    if (lane == 0) { w[0][wd] = sd; w[1][wd] = ss; w[2][wd] = sc; }
    __syncthreads();
    if (t == 0) {
        double Sd = w[0][0] + w[0][1] + w[0][2] + w[0][3];
        double Ss = w[1][0] + w[1][1] + w[1][2] + w[1][3];
        double Sc = w[2][0] + w[2][1] + w[2][2] + w[2][3];
        // off-diag ordered-pair sums for xx+yy: diag tiles (minus the exact-1
        // diagonal) count each ordered pair once; lower same-half tiles twice.
        double S_off = (Sd - 128.0 * (double)NPOS) + 2.0 * Ss;
        const double cnt_off = 64.0 * 63.0 * 62.0 * 62.0;   // per-set N*(N-1)*h*w
        const double cnt_all = 64.0 * 64.0 * 62.0 * 62.0;
        out[0] = (float)(S_off / cnt_off - 2.0 * Sc / cnt_all);
    }
}

// ================= fallback: verified R4 path (22.2 us) =================
#define HW 4096
#define HS 68
#define NPAIR_TRI 2016

template<int CTRL>
__device__ __forceinline__ double dpp_mov_d(double x) {
    long long xi = __double_as_longlong(x);
    int lo = __builtin_amdgcn_update_dpp(0, (int)(xi & 0xffffffffLL), CTRL, 0xf, 0xf, true);
    int hi = __builtin_amdgcn_update_dpp(0, (int)(((unsigned long long)xi) >> 32), CTRL, 0xf, 0xf, true);
    long long r = (long long)(((unsigned long long)(unsigned)lo) |
                              (((unsigned long long)(unsigned)hi) << 32));
    return __longlong_as_double(r);
}

__global__ __launch_bounds__(256) void mmd_pair_fb(
    const float* __restrict__ x, const float* __restrict__ y,
    double* __restrict__ partials)
{
    const int bid = blockIdx.x;
    const int t   = threadIdx.x;
    int type, i, j;
    if (bid < 2 * NPAIR_TRI) {
        type = (bid < NPAIR_TRI) ? 0 : 1;
        int k = bid - type * NPAIR_TRI;
        int ii = 0;
        while (k >= 63 - ii) { k -= 63 - ii; ++ii; }
        i = ii; j = ii + 1 + k;
    } else {
        type = 2;
        int pair = bid - 2 * NPAIR_TRI;
        i = pair >> 6; j = pair & 63;
    }
    const float* __restrict__ A = (type == 1 ? y : x) + i * HW;
    const float* __restrict__ B = (type == 0 ? x : y) + j * HW;
    __shared__ float hl[64 * HS];
    __shared__ double rsum[16];
    const float4* __restrict__ A4 = reinterpret_cast<const float4*>(A);
    const float4* __restrict__ B4 = reinterpret_cast<const float4*>(B);
    const int g = t & 15;
    #pragma unroll
    for (int k = 0; k < 4; ++k) {
        int e4 = t + k * 256;
        int r  = e4 >> 4;
        float4 a = A4[e4];
        float4 b = B4[e4];
        float dx = a.x - b.x, dy = a.y - b.y, dz = a.z - b.z, dw = a.w - b.w;
        dx *= dx; dy *= dy; dz *= dz; dw *= dw;
        float nx = dpp0_f<0x101>(dx);
        float ny = dpp0_f<0x101>(dy);
        float s1 = dy + dz;
        float s2 = dw + nx;
        float4 h;
        h.x = dx + s1; h.y = s1 + dw; h.z = dz + s2; h.w = s2 + ny;
        if (g == 15) { h.z = 1e30f; h.w = 1e30f; }
        *reinterpret_cast<float4*>(&hl[r * HS + 4 * g]) = h;
    }
    __syncthreads();
    const int g2 = t & 15, rc = t >> 4;
    const int base = 4 * g2;
    const int row0 = 4 * rc;
    const float NEG_SCALE = -1.0f / (40.5f * 0.69314718055994530942f);
    float accx = 0, accy = 0, accz = 0, accw = 0;
    float4 h0 = *reinterpret_cast<const float4*>(&hl[row0 * HS + base]);
    float4 h1 = *reinterpret_cast<const float4*>(&hl[(row0 + 1) * HS + base]);
    #pragma unroll
    for (int o = 0; o < 4; ++o) {
        int row = row0 + 2 + o;
        row = (row < 64) ? row : 63;
        float4 h2 = *reinterpret_cast<const float4*>(&hl[row * HS + base]);
        if (row0 + o < 62) {
            accx += EXP2F((h0.x + h1.x + h2.x) * NEG_SCALE);
            accy += EXP2F((h0.y + h1.y + h2.y) * NEG_SCALE);
            accz += EXP2F((h0.z + h1.z + h2.z) * NEG_SCALE);
            accw += EXP2F((h0.w + h1.w + h2.w) * NEG_SCALE);
        }
        h0 = h1; h1 = h2;
    }
    double lsum = ((double)accx + (double)accy) + ((double)accz + (double)accw);
    lsum += dpp_mov_d<0x111>(lsum);
    lsum += dpp_mov_d<0x112>(lsum);
    lsum += dpp_mov_d<0x114>(lsum);
    lsum += dpp_mov_d<0x118>(lsum);
    if ((t & 15) == 15) rsum[t >> 4] = lsum;
    __syncthreads();
    if (t == 0) {
        double s = 0.0;
        #pragma unroll
        for (int k = 0; k < 16; ++k) s += rsum[k];
        partials[bid] = s;
    }
}

__global__ __launch_bounds__(1024) void mmd_reduce_fb(
    const double* __restrict__ partials, float* __restrict__ out)
{
    const int t = threadIdx.x;
    double a_off = 0.0, a_xy = 0.0;
    for (int e = t; e < 2 * NPAIR_TRI; e += 1024) a_off += partials[e];
    for (int e = t; e < 4096;          e += 1024) a_xy  += partials[2 * NPAIR_TRI + e];
    const double cnt_off = 64.0 * 63.0 * 62.0 * 62.0;
    const double cnt_all = 64.0 * 64.0 * 62.0 * 62.0;
    double v = a_off * (2.0 / cnt_off) - a_xy * (2.0 / cnt_all);
    v += dpp_mov_d<0x111>(v);
    v += dpp_mov_d<0x112>(v);
    v += dpp_mov_d<0x114>(v);
    v += dpp_mov_d<0x118>(v);
    __shared__ double w[64];
    if ((t & 15) == 15) w[t >> 4] = v;
    __syncthreads();
    if (t == 0) {
        double s = 0.0;
        #pragma unroll
        for (int k = 0; k < 64; ++k) s += w[k];
        out[0] = (float)s;
    }
}

// ================= launch =================
extern "C" void kernel_launch(void* const* d_in, const int* in_sizes, int n_in,
                              void* d_out, int out_size, void* d_ws, size_t ws_size,
                              hipStream_t stream) {
    const float* x = (const float*)d_in[0];
    const float* y = (const float*)d_in[1];
    float* out = (float*)d_out;

    if (ws_size >= WSNEED) {
        unsigned char* rec = (unsigned char*)d_ws;
        float* part = (float*)((unsigned char*)d_ws + RECB);
        im2col_kernel<<<124, 256, 0, stream>>>(x, y, rec);
        mmd_mfma_kernel<<<961, 256, 0, stream>>>(rec, part);
        mmd_final_kernel<<<1, 256, 0, stream>>>(part, out);
    } else {
        double* partials = (double*)d_ws;   // 8128 doubles = 63.5 KiB
        mmd_pair_fb<<<2 * NPAIR_TRI + 4096, 256, 0, stream>>>(x, y, partials);
        mmd_reduce_fb<<<1, 1024, 0, stream>>>(partials, out);
    }
}

// Round 8
// 19.108 us; speedup vs baseline: 4.9877x; 1.8371x over previous
//
#include <hip/hip_runtime.h>

// PatchMMD via fused im2col + MFMA patch-GEMM (R8).
//   D(i,j,p,q) = ||patch_i(p,q) - patch_j(p,q)||^2  (3x3 VALID -> 62x62)
//   K = exp(-D/40.5);  out = offmean(Kxx) - 2*mean(Kxy) + offmean(Kyy)
//
// Identity: D = pre_i + pre_j - 2*<patch_i,patch_j>. Stack 128 images; the
// per-position 128x128 Gram matrix = K=9 GEMM -> mfma_f32_16x16x32_bf16,
// 8 diag tiles (diagonals ARE pre) + 28 strict-lower tiles (symmetry).
// Diagonal elements give exp2(~0)=1 -> subtract 128*3844 at combine.
// (Math path byte-identical to R7, which validated with absmax 0.0.)
//
// R8 structure: ONE fused kernel. Block = (p, q-octet), 512 threads:
//  - stage rows p..p+2 of all 128 images as bf16 in LDS (49 KB, stride 196)
//  - each wave owns one position q: builds 8 fragments from LDS
//    (9 masked u16 reads per group, n-stride 196*2B -> bank-conflict-free)
//  - verified R7 MFMA + epilogue + 3-way wave reduce
// Then a 1024-thread fp64 combine kernel.

typedef __attribute__((ext_vector_type(8))) short short8v;
typedef __attribute__((ext_vector_type(4))) float f32x4;

#define NPOS 3844        // 62*62
#define SIM  196         // LDS image stride, bf16 units (196*2B: 8B-aligned,
                         // n-stride = 98 dwords -> bank stride 2 -> 16 lanes
                         // hit 16 distinct banks)

#if __has_builtin(__builtin_amdgcn_exp2f)
#define EXP2F(v) __builtin_amdgcn_exp2f(v)
#else
#define EXP2F(v) __expf((v) * 0.69314718055994530942f)
#endif

// ---------------- DPP helpers (validated R4/R6/R7) ----------------
template<int CTRL>
__device__ __forceinline__ float dpp0_f(float v) {
    int r = __builtin_amdgcn_update_dpp(0, __float_as_int(v), CTRL, 0xf, 0xf, true);
    return __int_as_float(r);
}
template<int CTRL, int RM>
__device__ __forceinline__ float dppm_f(float v) {
    int r = __builtin_amdgcn_update_dpp(0, __float_as_int(v), CTRL, RM, 0xf, true);
    return __int_as_float(r);
}
__device__ __forceinline__ float wave_reduce_f(float v) {
    v += dpp0_f<0x111>(v);            // row_shr:1
    v += dpp0_f<0x112>(v);            // row_shr:2
    v += dpp0_f<0x114>(v);            // row_shr:4
    v += dpp0_f<0x118>(v);            // row_shr:8  -> lane 15 of each row
    v += dppm_f<0x142, 0xa>(v);       // bcast15 into rows 1,3
    v += dppm_f<0x143, 0xc>(v);       // bcast31 into rows 2,3 -> lane 63 total
    return v;
}

__device__ __forceinline__ unsigned int bf16rne(float f) {
    unsigned int u = __float_as_uint(f);
    return (u + 0x7fffu + ((u >> 16) & 1u)) >> 16;
}

// ---------------- fused kernel ----------------
__global__ __launch_bounds__(512) void mmd_fused_kernel(
    const float* __restrict__ x, const float* __restrict__ y,
    float* __restrict__ part)
{
    const int t = threadIdx.x, wid = t >> 6, lane = t & 63;
    const int p  = blockIdx.x >> 3;        // output row 0..61
    const int qg = blockIdx.x & 7;
    const int q  = qg * 8 + wid;           // 0..63; valid iff q < 62

    __shared__ unsigned short stg[128 * SIM];   // [n][u*64+c] bf16
    __shared__ float pre[8][128];

    // ---- stage rows p..p+2 of all 128 images as bf16 (RNE, same as R7) ----
    #pragma unroll
    for (int u = 0; u < 3; ++u) {
        #pragma unroll
        for (int k = 0; k < 4; ++k) {
            int it = t + k * 512;          // 0..2047 = [n 0..127][cg 0..15]
            int n = it >> 4, cg = it & 15;
            const float* img = (n < 64) ? (x + n * 4096) : (y + (n - 64) * 4096);
            float4 v = *reinterpret_cast<const float4*>(img + (p + u) * 64 + cg * 4);
            uint2 pk;
            pk.x = bf16rne(v.x) | (bf16rne(v.y) << 16);
            pk.y = bf16rne(v.z) | (bf16rne(v.w) << 16);
            *reinterpret_cast<uint2*>(&stg[n * SIM + u * 64 + cg * 4]) = pk;
        }
    }
    __syncthreads();

    // ---- build 8 shared A/B fragments for this wave's position ----
    // record semantics = R7: k = u*3+v (0..8), k>=9 zero.
    // lane layout (16x16x32): row/col = lane&15, k = (lane>>4)*8 + e.
    const int r = lane & 15, kg = lane >> 4;
    short8v frag[8];
    #pragma unroll
    for (int g = 0; g < 8; ++g) {
        const unsigned short* bp = &stg[(g * 16 + r) * SIM];
        short8v f = {0, 0, 0, 0, 0, 0, 0, 0};
        if (kg == 0) {                 // k = 0..7
            f[0] = (short)bp[q];
            f[1] = (short)bp[q + 1];
            f[2] = (short)bp[q + 2];
            f[3] = (short)bp[64 + q];
            f[4] = (short)bp[64 + q + 1];
            f[5] = (short)bp[64 + q + 2];
            f[6] = (short)bp[128 + q];
            f[7] = (short)bp[128 + q + 1];
        } else if (kg == 1) {          // k = 8
            f[0] = (short)bp[128 + q + 2];
        }
        frag[g] = f;
    }

    const float NS   = -1.0f / (40.5f * 0.69314718055994530942f);  // exp2 scale
    const float M2NS = -2.0f * NS;
    const f32x4 zf = {0.f, 0.f, 0.f, 0.f};

    // ---- diag tiles: Gram within group g; diagonal = pre ----
    f32x4 accd[8];
    #pragma unroll
    for (int g = 0; g < 8; ++g)
        accd[g] = __builtin_amdgcn_mfma_f32_16x16x32_bf16(frag[g], frag[g], zf, 0, 0, 0);

    // extract NS*diag to LDS. C/D: col=lane&15, row=(lane>>4)*4+m ->
    // holder iff (lane>>2)&3 == lane>>4, elem m = lane&3.
    const bool holder = ((lane >> 2) & 3) == kg;
    #pragma unroll
    for (int g = 0; g < 8; ++g) {
        float lo = (lane & 1) ? accd[g][1] : accd[g][0];
        float hi = (lane & 1) ? accd[g][3] : accd[g][2];
        float v  = (lane & 2) ? hi : lo;
        if (holder) pre[wid][g * 16 + (lane & 15)] = NS * v;
    }
    __syncthreads();

    // per-lane pre slices: pa[g][m] = this lane's C rows, pb[g] = its col
    float pa[8][4], pb[8];
    #pragma unroll
    for (int g = 0; g < 8; ++g) {
        const float* pp = &pre[wid][g * 16 + kg * 4];
        pa[g][0] = pp[0]; pa[g][1] = pp[1]; pa[g][2] = pp[2]; pa[g][3] = pp[3];
        pb[g] = pre[wid][g * 16 + (lane & 15)];
    }

    float acc_diag = 0.f, acc_same = 0.f, acc_cross = 0.f;

    // diag-tile epilogue (r==c elems give exp2(~0)=1, removed at combine)
    #pragma unroll
    for (int g = 0; g < 8; ++g)
        #pragma unroll
        for (int m = 0; m < 4; ++m)
            acc_diag += EXP2F(fmaf(accd[g][m], M2NS, pa[g][m] + pb[g]));

    // 28 strict-lower tiles: same-half weight 2 (symmetry), cross weight 1
    #pragma unroll
    for (int ti = 1; ti < 8; ++ti)
        #pragma unroll
        for (int tj = 0; tj < ti; ++tj) {
            f32x4 c4 = __builtin_amdgcn_mfma_f32_16x16x32_bf16(frag[ti], frag[tj], zf, 0, 0, 0);
            float e = 0.f;
            #pragma unroll
            for (int m = 0; m < 4; ++m)
                e += EXP2F(fmaf(c4[m], M2NS, pa[ti][m] + pb[tj]));
            if (ti >= 4 && tj < 4) acc_cross += e; else acc_same += e;
        }

    acc_diag  = wave_reduce_f(acc_diag);
    acc_same  = wave_reduce_f(acc_same);
    acc_cross = wave_reduce_f(acc_cross);
    if (lane == 63 && q < 62) {
        const int pid = p * 62 + q;
        part[pid]        = acc_diag;
        part[4096 + pid] = acc_same;
        part[8192 + pid] = acc_cross;
    }
}

// ---------------- fp64 combine ----------------
__global__ __launch_bounds__(1024) void mmd_final_kernel(
    const float* __restrict__ part, float* __restrict__ out)
{
    const int t = threadIdx.x;
    double sd = 0.0, ss = 0.0, sc = 0.0;
    for (int e = t; e < NPOS; e += 1024) {
        sd += (double)part[e];
        ss += (double)part[4096 + e];
        sc += (double)part[8192 + e];
    }
    #pragma unroll
    for (int off = 32; off > 0; off >>= 1) {
        sd += __shfl_xor(sd, off);
        ss += __shfl_xor(ss, off);
        sc += __shfl_xor(sc, off);
    }
    __shared__ double w[3][16];
    const int lane = t & 63, wd = t >> 6;
    if (lane == 0) { w[0][wd] = sd; w[1][wd] = ss; w[2][wd] = sc; }
    __syncthreads();
    if (t == 0) {
        double Sd = 0.0, Ss = 0.0, Sc = 0.0;
        #pragma unroll
        for (int k = 0; k < 16; ++k) { Sd += w[0][k]; Ss += w[1][k]; Sc += w[2][k]; }
        // xx+yy off-diag ordered sums: diag tiles (minus exact-1 diagonal)
        // count each ordered pair once; lower same-half tiles count twice.
        double S_off = (Sd - 128.0 * (double)NPOS) + 2.0 * Ss;
        const double cnt_off = 64.0 * 63.0 * 62.0 * 62.0;   // per-set N*(N-1)*h*w
        const double cnt_all = 64.0 * 64.0 * 62.0 * 62.0;
        out[0] = (float)(S_off / cnt_off - 2.0 * Sc / cnt_all);
    }
}

// ---------------- launch ----------------
extern "C" void kernel_launch(void* const* d_in, const int* in_sizes, int n_in,
                              void* d_out, int out_size, void* d_ws, size_t ws_size,
                              hipStream_t stream) {
    const float* x = (const float*)d_in[0];
    const float* y = (const float*)d_in[1];
    float* out  = (float*)d_out;
    float* part = (float*)d_ws;   // 3 * 4096 floats = 48 KiB

    mmd_fused_kernel<<<62 * 8, 512, 0, stream>>>(x, y, part);
    mmd_final_kernel<<<1, 1024, 0, stream>>>(part, out);
}